// Round 1
// baseline (573.398 us; speedup 1.0000x reference)
//
#include <hip/hip_runtime.h>
#include <hip/hip_bf16.h>
#include <hip/hip_fp16.h>

typedef unsigned int uint32;
typedef unsigned short ushort16;

#define TOK 1024
#define HID 2048
#define NEXP 64
#define TOPK 8
#define IMED 768
#define IMED2 1536

typedef __attribute__((ext_vector_type(8))) _Float16 half8;
typedef __attribute__((ext_vector_type(4))) float f32x4;

static __device__ __forceinline__ uint32 pack2(float a, float b) {
  union { _Float16 h[2]; uint32 u; } p;
  p.h[0] = (_Float16)a; p.h[1] = (_Float16)b;
  return p.u;
}
static __device__ __forceinline__ ushort16 f2h(float a) {
  union { _Float16 h; ushort16 u; } p;
  p.h = (_Float16)a;
  return p.u;
}

// ---------------- router: logits -> softmax -> top8 -> renorm ----------------
__global__ void router_kernel(const float* __restrict__ x, const float* __restrict__ gw,
                              int* __restrict__ topk_id, float* __restrict__ topk_w,
                              int* __restrict__ cnt) {
  int t = blockIdx.x;
  __shared__ __align__(16) float xs[HID];
  __shared__ float part[4][NEXP];
  __shared__ float logit[NEXP];
  const float* xr = x + (size_t)t * HID;
  for (int i = threadIdx.x; i < HID / 4; i += 256)
    ((float4*)xs)[i] = ((const float4*)xr)[i];
  __syncthreads();
  int e = threadIdx.x & 63, p = threadIdx.x >> 6;
  const float* wr = gw + (size_t)e * HID + p * 512;
  const float* xp = xs + p * 512;
  float s = 0.f;
  #pragma unroll 4
  for (int i = 0; i < 128; i++) {
    float4 w = ((const float4*)wr)[i];
    float4 xv = ((const float4*)xp)[i];
    s += w.x * xv.x + w.y * xv.y + w.z * xv.z + w.w * xv.w;
  }
  part[p][e] = s;
  __syncthreads();
  if (threadIdx.x < NEXP)
    logit[threadIdx.x] = part[0][threadIdx.x] + part[1][threadIdx.x] +
                         part[2][threadIdx.x] + part[3][threadIdx.x];
  __syncthreads();
  if (threadIdx.x == 0) {
    float m = -1e30f;
    for (int i = 0; i < NEXP; i++) m = fmaxf(m, logit[i]);
    float pr[NEXP]; float sum = 0.f;
    for (int i = 0; i < NEXP; i++) { pr[i] = __expf(logit[i] - m); sum += pr[i]; }
    float inv = 1.f / sum;
    int isel[TOPK]; float wsel[TOPK]; float wsum = 0.f;
    for (int k = 0; k < TOPK; k++) {
      float best = -1.f; int bi = 0;
      for (int i = 0; i < NEXP; i++) if (pr[i] > best) { best = pr[i]; bi = i; }
      pr[bi] = -2.f;
      isel[k] = bi; wsel[k] = best * inv; wsum += best * inv;
      atomicAdd(&cnt[bi], 1);
    }
    float rinv = 1.f / wsum;
    for (int k = 0; k < TOPK; k++) {
      topk_id[t * TOPK + k] = isel[k];
      topk_w[t * TOPK + k] = wsel[k] * rinv;
    }
  }
}

__global__ void scan_kernel(const int* __restrict__ cnt, int* __restrict__ off,
                            int* __restrict__ cur) {
  if (threadIdx.x == 0) {
    int a = 0;
    for (int e = 0; e < NEXP; e++) { off[e] = a; cur[e] = a; a += cnt[e]; }
    off[NEXP] = a;
  }
}

__global__ void scatter_kernel(const int* __restrict__ topk_id, const float* __restrict__ topk_w,
                               int* __restrict__ cur, int* __restrict__ row_tok,
                               float* __restrict__ row_w) {
  int i = blockIdx.x * 256 + threadIdx.x;  // 8192 pairs
  int e = topk_id[i];
  int p = atomicAdd(&cur[e], 1);
  row_tok[p] = i >> 3;
  row_w[p] = topk_w[i];
}

// ---------------- grouped gate_up GEMM + SwiGLU ----------------
// BM=256, BN=64 per half (gate & up), BK=32, 512 threads (8 waves: 4m x 2n)
__global__ __launch_bounds__(512) void gateup_kernel(
    const float* __restrict__ x, const float* __restrict__ Wgu,
    const int* __restrict__ off, const int* __restrict__ row_tok,
    ushort16* __restrict__ act) {
  int e = blockIdx.z;
  int r0 = off[e];
  int ne = off[e + 1] - r0;
  int m0 = blockIdx.y << 8;
  if (m0 >= ne) return;
  int i0 = blockIdx.x << 6;

  __shared__ __align__(16) ushort16 As[256 * 40];
  __shared__ __align__(16) ushort16 Bs[2 * 64 * 40];

  int tid = threadIdx.x;
  int lane = tid & 63;
  int wid = tid >> 6;
  int wm = wid >> 1, wn = wid & 1;
  int fr = lane & 15, hi = lane >> 4;

  // A staging: 2 threads per row, 16 floats each
  int arow = tid >> 1, aseg = tid & 1;
  int grow = m0 + arow;
  int tok = (grow < ne) ? row_tok[r0 + grow] : 0;
  const float* xrow = x + (size_t)tok * HID + (aseg << 4);

  // B staging: halves x 256 threads; thread -> 4 cols x 2 k-rows
  int bhalf = tid >> 8, bs = tid & 255;
  int bn = (bs & 15) << 2;
  int bk = (bs >> 4) << 1;
  const float* wp = Wgu + (size_t)e * HID * IMED2 + (size_t)bk * IMED2 +
                    (bhalf ? (IMED + i0 + bn) : (i0 + bn));

  f32x4 accg[4][2], accu[4][2];
  #pragma unroll
  for (int a = 0; a < 4; a++)
    #pragma unroll
    for (int b = 0; b < 2; b++) { accg[a][b] = (f32x4)0.f; accu[a][b] = (f32x4)0.f; }

  char* AsB = (char*)As;
  char* BsB = (char*)Bs;

  for (int k0 = 0; k0 < HID; k0 += 32) {
    float4 a0 = *(const float4*)(xrow + k0 + 0);
    float4 a1 = *(const float4*)(xrow + k0 + 4);
    float4 a2 = *(const float4*)(xrow + k0 + 8);
    float4 a3 = *(const float4*)(xrow + k0 + 12);
    float4 w0 = *(const float4*)(wp + (size_t)k0 * IMED2);
    float4 w1 = *(const float4*)(wp + (size_t)k0 * IMED2 + IMED2);
    __syncthreads();
    uint4 lo, hh;
    lo.x = pack2(a0.x, a0.y); lo.y = pack2(a0.z, a0.w);
    lo.z = pack2(a1.x, a1.y); lo.w = pack2(a1.z, a1.w);
    hh.x = pack2(a2.x, a2.y); hh.y = pack2(a2.z, a2.w);
    hh.z = pack2(a3.x, a3.y); hh.w = pack2(a3.z, a3.w);
    *(uint4*)(AsB + arow * 80 + (aseg << 5)) = lo;
    *(uint4*)(AsB + arow * 80 + (aseg << 5) + 16) = hh;
    {
      float g0[4] = {w0.x, w0.y, w0.z, w0.w};
      float g1[4] = {w1.x, w1.y, w1.z, w1.w};
      #pragma unroll
      for (int j = 0; j < 4; j++) {
        int n = bn + j;
        uint32 pr = pack2(g0[j], g1[j]);
        int byt = (bhalf * 64 + n) * 80 + ((((bk >> 3) ^ (n >> 2)) & 3) << 4) + ((bk & 7) << 1);
        *(uint32*)(BsB + byt) = pr;
      }
    }
    __syncthreads();
    half8 af[4];
    #pragma unroll
    for (int mi = 0; mi < 4; mi++)
      af[mi] = *(half8*)(AsB + ((wm << 6) + (mi << 4) + fr) * 80 + (hi << 4));
    #pragma unroll
    for (int ni = 0; ni < 2; ni++) {
      int n = (wn << 5) + (ni << 4) + fr;
      int swz = ((hi ^ (n >> 2)) & 3) << 4;
      half8 bg = *(half8*)(BsB + n * 80 + swz);
      half8 bu = *(half8*)(BsB + (64 + n) * 80 + swz);
      #pragma unroll
      for (int mi = 0; mi < 4; mi++) {
        accg[mi][ni] = __builtin_amdgcn_mfma_f32_16x16x32_f16(af[mi], bg, accg[mi][ni], 0, 0, 0);
        accu[mi][ni] = __builtin_amdgcn_mfma_f32_16x16x32_f16(af[mi], bu, accu[mi][ni], 0, 0, 0);
      }
    }
  }
  // epilogue: SwiGLU -> act (f16 bits in ushort)
  #pragma unroll
  for (int mi = 0; mi < 4; mi++) {
    #pragma unroll
    for (int ni = 0; ni < 2; ni++) {
      int col = i0 + (wn << 5) + (ni << 4) + fr;
      #pragma unroll
      for (int r = 0; r < 4; r++) {
        int rr = m0 + (wm << 6) + (mi << 4) + (hi << 2) + r;
        if (rr < ne) {
          float g = accg[mi][ni][r];
          float u = accu[mi][ni][r];
          float s = g / (1.f + __expf(-g)) * u;
          act[(size_t)(r0 + rr) * IMED + col] = f2h(s);
        }
      }
    }
  }
}

// ---------------- grouped down GEMM + weighted scatter-add ----------------
__global__ __launch_bounds__(512) void down_kernel(
    const ushort16* __restrict__ act, const float* __restrict__ Wd,
    const int* __restrict__ off, const int* __restrict__ row_tok,
    const float* __restrict__ row_w, float* __restrict__ out) {
  int e = blockIdx.z;
  int r0 = off[e];
  int ne = off[e + 1] - r0;
  int m0 = blockIdx.y << 8;
  if (m0 >= ne) return;
  int n0 = blockIdx.x << 6;

  __shared__ __align__(16) ushort16 As[256 * 40];
  __shared__ __align__(16) ushort16 Bs[64 * 40];

  int tid = threadIdx.x;
  int lane = tid & 63;
  int wid = tid >> 6;
  int wm = wid >> 1, wn = wid & 1;
  int fr = lane & 15, hi = lane >> 4;

  int arow = tid >> 1, aseg = tid & 1;
  int grow = m0 + arow;
  bool avalid = grow < ne;
  const ushort16* arp = act + (size_t)(r0 + (avalid ? grow : 0)) * IMED + (aseg << 4);

  int bs = tid & 255;
  int bn = (bs & 15) << 2;
  int bk = (bs >> 4) << 1;
  const float* wp = Wd + (size_t)e * IMED * HID + (size_t)bk * HID + n0 + bn;

  f32x4 acc[4][2];
  #pragma unroll
  for (int a = 0; a < 4; a++)
    #pragma unroll
    for (int b = 0; b < 2; b++) acc[a][b] = (f32x4)0.f;

  char* AsB = (char*)As;
  char* BsB = (char*)Bs;

  for (int k0 = 0; k0 < IMED; k0 += 32) {
    uint4 va = {0, 0, 0, 0}, vb = {0, 0, 0, 0};
    if (avalid) {
      va = *(const uint4*)(arp + k0);
      vb = *(const uint4*)(arp + k0 + 8);
    }
    float4 w0 = {0, 0, 0, 0}, w1 = {0, 0, 0, 0};
    if (tid < 256) {
      w0 = *(const float4*)(wp + (size_t)k0 * HID);
      w1 = *(const float4*)(wp + (size_t)k0 * HID + HID);
    }
    __syncthreads();
    *(uint4*)(AsB + arow * 80 + (aseg << 5)) = va;
    *(uint4*)(AsB + arow * 80 + (aseg << 5) + 16) = vb;
    if (tid < 256) {
      float g0[4] = {w0.x, w0.y, w0.z, w0.w};
      float g1[4] = {w1.x, w1.y, w1.z, w1.w};
      #pragma unroll
      for (int j = 0; j < 4; j++) {
        int n = bn + j;
        uint32 pr = pack2(g0[j], g1[j]);
        int byt = n * 80 + ((((bk >> 3) ^ (n >> 2)) & 3) << 4) + ((bk & 7) << 1);
        *(uint32*)(BsB + byt) = pr;
      }
    }
    __syncthreads();
    half8 af[4];
    #pragma unroll
    for (int mi = 0; mi < 4; mi++)
      af[mi] = *(half8*)(AsB + ((wm << 6) + (mi << 4) + fr) * 80 + (hi << 4));
    #pragma unroll
    for (int ni = 0; ni < 2; ni++) {
      int n = (wn << 5) + (ni << 4) + fr;
      half8 bf_ = *(half8*)(BsB + n * 80 + (((hi ^ (n >> 2)) & 3) << 4));
      #pragma unroll
      for (int mi = 0; mi < 4; mi++)
        acc[mi][ni] = __builtin_amdgcn_mfma_f32_16x16x32_f16(af[mi], bf_, acc[mi][ni], 0, 0, 0);
    }
  }
  #pragma unroll
  for (int mi = 0; mi < 4; mi++) {
    #pragma unroll
    for (int r = 0; r < 4; r++) {
      int rr = m0 + (wm << 6) + (mi << 4) + (hi << 2) + r;
      if (rr < ne) {
        float w = row_w[r0 + rr];
        int t = row_tok[r0 + rr];
        #pragma unroll
        for (int ni = 0; ni < 2; ni++) {
          int col = n0 + (wn << 5) + (ni << 4) + fr;
          unsafeAtomicAdd(&out[(size_t)t * HID + col], acc[mi][ni][r] * w);
        }
      }
    }
  }
}

// ---------------- launch ----------------
extern "C" void kernel_launch(void* const* d_in, const int* in_sizes, int n_in,
                              void* d_out, int out_size, void* d_ws, size_t ws_size,
                              hipStream_t stream) {
  const float* x = (const float*)d_in[0];
  const float* gw = (const float*)d_in[1];
  const float* wgu = (const float*)d_in[2];
  const float* wd = (const float*)d_in[3];
  float* out = (float*)d_out;
  char* ws = (char*)d_ws;

  int* cnt = (int*)(ws + 0);
  int* cur = (int*)(ws + 256);
  int* off = (int*)(ws + 512);
  int* topk_id = (int*)(ws + 1024);
  float* topk_w = (float*)(ws + 1024 + 32768);
  int* row_tok = (int*)(ws + 1024 + 65536);
  float* row_w = (float*)(ws + 1024 + 98304);
  ushort16* act = (ushort16*)(ws + 135168);

  hipMemsetAsync(cnt, 0, 256, stream);
  router_kernel<<<TOK, 256, 0, stream>>>(x, gw, topk_id, topk_w, cnt);
  scan_kernel<<<1, 64, 0, stream>>>(cnt, off, cur);
  scatter_kernel<<<TOK * TOPK / 256, 256, 0, stream>>>(topk_id, topk_w, cur, row_tok, row_w);
  hipMemsetAsync(out, 0, (size_t)TOK * HID * sizeof(float), stream);
  gateup_kernel<<<dim3(IMED / 64, 4, NEXP), 512, 0, stream>>>(x, wgu, off, row_tok, act);
  down_kernel<<<dim3(HID / 64, 4, NEXP), 512, 0, stream>>>(act, wd, off, row_tok, row_w, out);
}